// Round 14
// baseline (592.080 us; speedup 1.0000x reference)
//
#include <hip/hip_runtime.h>
#include <stdint.h>

#define Bb 8
#define Tt 512
#define Vv 32000
#define Hh 1024
#define Ss 256
#define Ee 8
#define LEe 2
#define LMm 4
#define Mm (Bb*Tt)        // 4096
#define MKk (Bb*2*Tt)     // 8192

typedef unsigned short u16;
typedef __bf16 bf16x8 __attribute__((ext_vector_type(8)));
typedef float f32x4 __attribute__((ext_vector_type(4)));

__device__ __forceinline__ u16 f2bf(float f) {
  union { float f; uint32_t u; } c; c.f = f;
  uint32_t u = c.u;
  uint32_t r = (u + 0x7FFFu + ((u >> 16) & 1u)) >> 16;
  return (u16)r;
}

// ---------------------------------------------------------------------------
// 256x256 bf16 MFMA GEMM (head), 8-phase, 16 waves, READ-AHEAD-BY-ONE-PHASE.
// Each phase reads the NEXT phase's A-frags (and next-kh B-frags on mh=1
// phases) into ping-pong register sets af[2][2] / bf2[2][4], right after its
// lgkmcnt(0) (or after the vmcnt on wait-phases P4/P8). The ~1000-cyc LDS
// drain then overlaps MFMA+barriers+stage of the current phase instead of
// serializing in front of every MFMA cluster (r13: 1613 cyc/phase vs m201's
// 824 at identical per-phase work — drain was the gap).
// Waits: vmcnt(2) at P4/P8 (race-free ledger; r11's vmcnt(4) had a P7 race).
// Ledger (verified): every read-ahead's slot staged >=2 phases earlier and
// retired by the last wait; every restage >=2 barrier-separated phases after
// the slot's final read. Prologue reads P1's frags after its vmcnt(2).
// ---------------------------------------------------------------------------
#define PH(MH_C, AS_C, BS_C, AN_CUR, AN_KH, AN_MH, AS_N, RDB, BN_CUR, BN_KH, BS_N, STAGECALL, WAITV) \
  {                                                                            \
    STAGECALL;                                                                 \
    __builtin_amdgcn_sched_barrier(0);                                         \
    __builtin_amdgcn_s_barrier();                                              \
    asm volatile("s_waitcnt lgkmcnt(0)" ::: "memory");                         \
    __builtin_amdgcn_sched_barrier(0);                                         \
    if (!(WAITV)) {                                                            \
      af[AS_N][0] = *(const bf16x8*)&As[AN_CUR][AN_KH][aoffs[(AN_MH)*2]];      \
      af[AS_N][1] = *(const bf16x8*)&As[AN_CUR][AN_KH][aoffs[(AN_MH)*2+1]];    \
      if (RDB) {                                                               \
        _Pragma("unroll")                                                      \
        for (int ni = 0; ni < 4; ni++)                                         \
          bf2[BS_N][ni] = *(const bf16x8*)&Bs[BN_CUR][BN_KH][boffs[ni]];       \
      }                                                                        \
    }                                                                          \
    __builtin_amdgcn_s_setprio(1);                                             \
    _Pragma("unroll")                                                          \
    for (int ni = 0; ni < 4; ni++) {                                           \
      acc[(MH_C)*2][ni]   = __builtin_amdgcn_mfma_f32_16x16x32_bf16(af[AS_C][0], bf2[BS_C][ni], acc[(MH_C)*2][ni], 0, 0, 0);   \
      acc[(MH_C)*2+1][ni] = __builtin_amdgcn_mfma_f32_16x16x32_bf16(af[AS_C][1], bf2[BS_C][ni], acc[(MH_C)*2+1][ni], 0, 0, 0); \
    }                                                                          \
    __builtin_amdgcn_s_setprio(0);                                             \
    __builtin_amdgcn_sched_barrier(0);                                         \
    if (WAITV) {                                                               \
      asm volatile("s_waitcnt vmcnt(2)" ::: "memory");                         \
      af[AS_N][0] = *(const bf16x8*)&As[AN_CUR][AN_KH][aoffs[(AN_MH)*2]];      \
      af[AS_N][1] = *(const bf16x8*)&As[AN_CUR][AN_KH][aoffs[(AN_MH)*2+1]];    \
      if (RDB) {                                                               \
        _Pragma("unroll")                                                      \
        for (int ni = 0; ni < 4; ni++)                                         \
          bf2[BS_N][ni] = *(const bf16x8*)&Bs[BN_CUR][BN_KH][boffs[ni]];       \
      }                                                                        \
    }                                                                          \
    __builtin_amdgcn_s_barrier();                                              \
    __builtin_amdgcn_sched_barrier(0);                                         \
  }

__global__ __launch_bounds__(1024, 2)
void gemm256(const u16* __restrict__ A, const u16* __restrict__ Bw,
             int nbn, int N, int K, float* __restrict__ outF)
{
  __shared__ u16 As[2][2][256*32];
  __shared__ u16 Bs[2][2][256*32];

  const int id  = blockIdx.x;
  const int per = gridDim.x >> 3;
  const int vid = (id & 7) * per + (id >> 3);
  const int bn  = vid % nbn;
  const int bm  = vid / nbn;

  const int t = threadIdx.x;
  const int lane = t & 63;
  const int w = t >> 6;
  const int wr = w >> 2, wc = w & 3;
  const int l16 = lane & 15, lhi = lane >> 4;

  const long long arow0 = (long long)bm * 256;
  const long long brow0 = (long long)bn * 256;

  int aoffs[4], boffs[4];
#pragma unroll
  for (int mi = 0; mi < 4; mi++) {
    const int r = wr * 64 + mi * 16 + l16;
    aoffs[mi] = r * 32 + (lhi ^ ((r >> 1) & 3)) * 8;
  }
#pragma unroll
  for (int ni = 0; ni < 4; ni++) {
    const int r = wc * 64 + ni * 16 + l16;
    boffs[ni] = r * 32 + (lhi ^ ((r >> 1) & 3)) * 8;
  }

  const int sr = t >> 2;
  const int sc = (t & 3) ^ ((sr >> 1) & 3);
  const long long sAo = (arow0 + sr) * (long long)K + sc * 8;
  const long long sBo = (brow0 + sr) * (long long)K + sc * 8;
  const int ldsd = t * 8;

  f32x4 acc[4][4];
#pragma unroll
  for (int i = 0; i < 4; i++)
#pragma unroll
    for (int j = 0; j < 4; j++) acc[i][j] = (f32x4){0.f, 0.f, 0.f, 0.f};

  auto SA = [&](int b, int kh, int k0) {
    __builtin_amdgcn_global_load_lds(
        (const __attribute__((address_space(1))) void*)(A + sAo + k0 + kh * 32),
        (__attribute__((address_space(3))) void*)(&As[b][kh][ldsd]), 16, 0, 0);
  };
  auto SB = [&](int b, int kh, int k0) {
    __builtin_amdgcn_global_load_lds(
        (const __attribute__((address_space(1))) void*)(Bw + sBo + k0 + kh * 32),
        (__attribute__((address_space(3))) void*)(&Bs[b][kh][ldsd]), 16, 0, 0);
  };

  bf16x8 af[2][2];
  bf16x8 bf2[2][4];

  const int NT = K >> 6;

  // prologue: stage (0,kh0),(0,kh1),(1,kh0); vmcnt(2) retires (0,*) slots;
  // then read P1's frags (A(0,0,mh0) -> set0, B(0,0) -> bset0).
  SA(0, 0, 0); SB(0, 0, 0);
  SA(0, 1, 0); SB(0, 1, 0);
  SA(1, 0, 64); SB(1, 0, 64);
  asm volatile("s_waitcnt vmcnt(2)" ::: "memory");
  __builtin_amdgcn_s_barrier();
  af[0][0] = *(const bf16x8*)&As[0][0][aoffs[0]];
  af[0][1] = *(const bf16x8*)&As[0][0][aoffs[1]];
#pragma unroll
  for (int ni = 0; ni < 4; ni++)
    bf2[0][ni] = *(const bf16x8*)&Bs[0][0][boffs[ni]];
  __builtin_amdgcn_sched_barrier(0);

  for (int it = 0; it < (NT >> 1); ++it) {
    const int k1 = (2 * it + 1) << 6;
    const int t2 = 2 * it + 2, t3 = 2 * it + 3;
    const int k2 = (t2 < NT ? t2 : NT - 1) << 6;
    const int k3 = (t3 < NT ? t3 : NT - 1) << 6;
    //  MH_C AS_C BS_C | next-A: cur kh mh -> AS_N | RDB next-B: cur kh -> BS_N
    PH(0, 0, 0,  0, 0, 1, 1,  0, 0, 0, 0, SA(1, 1, k1), 0)   // P1
    PH(1, 1, 0,  0, 1, 0, 0,  1, 0, 1, 1, SB(1, 1, k1), 0)   // P2
    PH(0, 0, 1,  0, 1, 1, 1,  0, 0, 0, 0, SA(0, 0, k2), 0)   // P3
    PH(1, 1, 1,  1, 0, 0, 0,  1, 1, 0, 0, SB(0, 0, k2), 1)   // P4
    PH(0, 0, 0,  1, 0, 1, 1,  0, 0, 0, 0, SA(0, 1, k2), 0)   // P5
    PH(1, 1, 0,  1, 1, 0, 0,  1, 1, 1, 1, SB(0, 1, k2), 0)   // P6
    PH(0, 0, 1,  1, 1, 1, 1,  0, 0, 0, 0, SA(1, 0, k3), 0)   // P7
    PH(1, 1, 1,  0, 0, 0, 0,  1, 0, 0, 0, SB(1, 0, k3), 1)   // P8
  }

#pragma unroll
  for (int mi = 0; mi < 4; mi++) {
#pragma unroll
    for (int rr = 0; rr < 4; rr++) {
      const long long grow = arow0 + wr * 64 + mi * 16 + lhi * 4 + rr;
#pragma unroll
      for (int ni = 0; ni < 4; ni++) {
        const long long gcol = brow0 + wc * 64 + ni * 16 + l16;
        outF[grow * N + gcol] = acc[mi][ni][rr];
      }
    }
  }
}

// ---------------------------------------------------------------------------
// Small GEMM, 64x64 tile, 4 waves, 4 blocks/CU. All small/mid GEMMs.
// MODE 0: outB = bf16(silu(acc)); MODE 1: outF = res + 0.1*acc, outB = bf16.
// 64-row maps: broadcast src0(bm) = (bm>>4)*512 + (bm&7)*64; esel[bm>>3].
// ---------------------------------------------------------------------------
template<int MODE>
__global__ __launch_bounds__(256, 4)
void gemmS(const u16* __restrict__ A, const u16* __restrict__ Bw,
           int nbm, int N, int K,
           const float* __restrict__ res, float* __restrict__ outF,
           u16* __restrict__ outB,
           const int* __restrict__ esel, long long estride,
           int mapA, int mapRes)
{
  __shared__ u16 As[2][64*64];
  __shared__ u16 Bs[2][64*64];

  const int id  = blockIdx.x;
  const int per = gridDim.x >> 3;
  const int vid = (id & 7) * per + (id >> 3);
  const int bm  = vid % nbm;
  const int bn  = vid / nbm;

  const int t = threadIdx.x;
  const int w = t >> 6, lane = t & 63;
  const int wr = w >> 1, wc = w & 1;
  const int l16 = lane & 15, lhi = lane >> 4;

  const u16* Bp = Bw;
  if (esel) Bp += (long long)esel[bm >> 3] * estride;

  const long long mrow0 = (long long)(bm >> 4) * 512 + (long long)(bm & 7) * 64;
  const long long arow0 = (long long)bm * 64;
  const long long asrc0 = mapA ? mrow0 : arow0;
  const long long rrow0 = mapRes ? mrow0 : arow0;
  const long long brow0 = (long long)bn * 64;

  long long aoff[2], boff[2];
  int ldso[2];
#pragma unroll
  for (int i = 0; i < 2; ++i) {
    const int g  = i * 256 + t;
    const int r  = g >> 3;
    const int pc = g & 7;
    const int c  = pc ^ (r & 7);
    aoff[i] = (asrc0 + r) * (long long)K + c * 8;
    boff[i] = (brow0 + r) * (long long)K + c * 8;
    ldso[i] = g * 8;
  }

  f32x4 acc[2][2];
#pragma unroll
  for (int i = 0; i < 2; i++)
#pragma unroll
    for (int j = 0; j < 2; j++) acc[i][j] = (f32x4){0.f, 0.f, 0.f, 0.f};

  auto STAGE = [&](int bsel, int k0) {
#pragma unroll
    for (int i = 0; i < 2; ++i)
      __builtin_amdgcn_global_load_lds(
          (const __attribute__((address_space(1))) void*)(A + aoff[i] + k0),
          (__attribute__((address_space(3))) void*)(&As[bsel][ldso[i]]), 16, 0, 0);
#pragma unroll
    for (int i = 0; i < 2; ++i)
      __builtin_amdgcn_global_load_lds(
          (const __attribute__((address_space(1))) void*)(Bp + boff[i] + k0),
          (__attribute__((address_space(3))) void*)(&Bs[bsel][ldso[i]]), 16, 0, 0);
  };

  const int rowA = (wr * 32 + l16) * 64;
  const int rowB = (wc * 32 + l16) * 64;
  const int x7   = l16 & 7;

  const int NT = K >> 6;

  STAGE(0, 0);
  asm volatile("s_waitcnt vmcnt(0)" ::: "memory");
  __builtin_amdgcn_s_barrier();

  for (int tile = 0; tile < NT; ++tile) {
    const int cur = tile & 1;
    if (tile + 1 < NT) STAGE(cur ^ 1, (tile + 1) << 6);

#pragma unroll
    for (int s = 0; s < 2; ++s) {
      bf16x8 af[2], bfv[2];
      const int swz = ((s * 4 + lhi) ^ x7) * 8;
#pragma unroll
      for (int mi = 0; mi < 2; mi++)
        af[mi] = *(const bf16x8*)&As[cur][rowA + mi * 1024 + swz];
#pragma unroll
      for (int ni = 0; ni < 2; ni++)
        bfv[ni] = *(const bf16x8*)&Bs[cur][rowB + ni * 1024 + swz];
      __builtin_amdgcn_s_setprio(1);
#pragma unroll
      for (int mi = 0; mi < 2; mi++)
#pragma unroll
        for (int ni = 0; ni < 2; ni++)
          acc[mi][ni] = __builtin_amdgcn_mfma_f32_16x16x32_bf16(af[mi], bfv[ni], acc[mi][ni], 0, 0, 0);
      __builtin_amdgcn_s_setprio(0);
    }

    if (tile + 1 < NT) {
      asm volatile("s_waitcnt vmcnt(0)" ::: "memory");
      __builtin_amdgcn_s_barrier();
    }
  }

#pragma unroll
  for (int mi = 0; mi < 2; mi++) {
#pragma unroll
    for (int rr = 0; rr < 4; rr++) {
      const long long lrow = wr * 32 + mi * 16 + lhi * 4 + rr;
      const long long grow = arow0 + lrow;
#pragma unroll
      for (int ni = 0; ni < 2; ni++) {
        const long long gcol = brow0 + wc * 32 + ni * 16 + l16;
        const long long idx  = grow * N + gcol;
        float v = acc[mi][ni][rr];
        if (MODE == 0) {
          float s = v / (1.f + expf(-v));
          outB[idx] = f2bf(s);
        } else {
          float o = res[(rrow0 + lrow) * N + gcol] + 0.1f * v;
          outF[idx] = o;
          outB[idx] = f2bf(o);
        }
      }
    }
  }
}

// ---------------------------------------------------------------------------
// Fused prep: ONE dispatch for head cvt + 4 weight transposes + embed gather.
// ---------------------------------------------------------------------------
__device__ __forceinline__ void tr_tile(const float* __restrict__ in,
                                        u16* __restrict__ out,
                                        int R, int C, int j, int t) {
  __shared__ float tile[32][33];
  const int ntx = C >> 5, nty = R >> 5;
  const int b = j / (ntx * nty);
  const int rem = j % (ntx * nty);
  const int c0 = (rem % ntx) * 32, r0 = (rem / ntx) * 32;
  const float* src = in  + (size_t)b * R * C;
  u16*         dst = out + (size_t)b * R * C;
  const int tx = t & 31, ty = t >> 5;
#pragma unroll
  for (int i = 0; i < 4; ++i)
    tile[ty * 4 + i][tx] = src[(size_t)(r0 + ty * 4 + i) * C + c0 + tx];
  __syncthreads();
#pragma unroll
  for (int i = 0; i < 4; ++i)
    dst[(size_t)(c0 + ty * 4 + i) * R + r0 + tx] = f2bf(tile[tx][ty * 4 + i]);
}

__global__ __launch_bounds__(256)
void k_prep(const float* __restrict__ hw, u16* __restrict__ hwb,
            const float* __restrict__ bw1, u16* __restrict__ w1t,
            const float* __restrict__ bw2, u16* __restrict__ w2t,
            const float* __restrict__ ew1, u16* __restrict__ e1t,
            const float* __restrict__ ew2, u16* __restrict__ e2t,
            const int* __restrict__ tokens, const float* __restrict__ embed,
            float* __restrict__ x, u16* __restrict__ xb)
{
  const int bid = blockIdx.x;
  const int t = threadIdx.x;
  if (bid < 2048) {
    const size_t n4 = (size_t)Vv * Hh / 4;
    for (size_t i = (size_t)bid * 256 + t; i < n4; i += 2048 * 256) {
      float4 v = ((const float4*)hw)[i];
      ushort4 u;
      u.x = f2bf(v.x); u.y = f2bf(v.y); u.z = f2bf(v.z); u.w = f2bf(v.w);
      ((ushort4*)hwb)[i] = u;
    }
  } else if (bid < 3072) {
    tr_tile(bw1, w1t, Hh, Ss, bid - 2048, t);
  } else if (bid < 4096) {
    tr_tile(bw2, w2t, Ss, Hh, bid - 3072, t);
  } else if (bid < 8192) {
    tr_tile(ew1, e1t, Hh, Ss, bid - 4096, t);
  } else if (bid < 12288) {
    tr_tile(ew2, e2t, Ss, Hh, bid - 8192, t);
  } else {
    const int row = bid - 12288;
    const int tok = tokens[row];
    float4 v = ((const float4*)(embed + (size_t)tok * Hh))[t];
    ((float4*)(x + (size_t)row * Hh))[t] = v;
    ushort4 u;
    u.x = f2bf(v.x); u.y = f2bf(v.y); u.z = f2bf(v.z); u.w = f2bf(v.w);
    ((ushort4*)(xb + (size_t)row * Hh))[t] = u;
  }
}

// column-mean stage 1
__global__ __launch_bounds__(1024) void k_cmean1(const float* __restrict__ x, float* __restrict__ part) {
  int b = blockIdx.x >> 3, ch = blockIdx.x & 7;
  int col = threadIdx.x;
  float s = 0.f;
  for (int t = ch * 64; t < ch * 64 + 64; ++t)
    s += x[((size_t)b * Tt + t) * Hh + col];
  part[(size_t)blockIdx.x * Hh + col] = s;
}

// routing: 8 blocks (one per sequence), 1024 threads
__global__ __launch_bounds__(1024) void k_route(const float* __restrict__ part,
                                                const float* __restrict__ rw,
                                                int* __restrict__ t2i, float* __restrict__ t2w) {
  __shared__ float xm[Hh];
  __shared__ float lg[16];
  const int b = blockIdx.x;
  const int t = threadIdx.x;
  float s = 0.f;
#pragma unroll
  for (int ch = 0; ch < 8; ch++) s += part[(size_t)(b * 8 + ch) * Hh + t];
  xm[t] = s;
  __syncthreads();
  const int w = t >> 6, lane = t & 63;
  if (w < Ee) {
    float d = 0.f;
    for (int j = lane; j < Hh; j += 64)
      d += xm[j] * rw[(size_t)w * Hh + j];
    for (int off = 32; off; off >>= 1) d += __shfl_xor(d, off, 64);
    if (lane == 0) lg[w] = d * (2.f / (float)Tt);
  }
  __syncthreads();
  if (t == 0) {
    float logits[Ee];
#pragma unroll
    for (int e = 0; e < Ee; e++) logits[e] = lg[e];
    float mx = logits[0];
    for (int e = 1; e < Ee; e++) mx = fmaxf(mx, logits[e]);
    float pr[Ee], den = 0.f;
    for (int e = 0; e < Ee; e++) { pr[e] = expf(logits[e] - mx); den += pr[e]; }
    for (int e = 0; e < Ee; e++) pr[e] /= den;
    int i1 = 0;
    for (int e = 1; e < Ee; e++) if (pr[e] > pr[i1]) i1 = e;
    int i2 = -1;
    for (int e = 0; e < Ee; e++) { if (e == i1) continue; if (i2 < 0 || pr[e] > pr[i2]) i2 = e; }
    float eb = expf(pr[i2] - pr[i1]);
    float w0 = 1.f / (1.f + eb);
    float w1 = eb / (1.f + eb);
    t2i[b * 2]     = i1;  t2i[b * 2 + 1] = i2;
    t2w[b * 2]     = w0;  t2w[b * 2 + 1] = w1;
  }
}

// fused combine + RMSNorm: o = x + w0*xk[b,0] + w1*xk[b,1]; xb = bf16(rms(o))
__global__ __launch_bounds__(256) void k_combnorm(const float* __restrict__ x,
                                                  const float* __restrict__ xk,
                                                  const float* __restrict__ wgt,
                                                  const float* __restrict__ nw,
                                                  u16* __restrict__ xnb) {
  int row = blockIdx.x, t = threadIdx.x;
  int b = row >> 9, tt = row & 511;
  size_t r0 = (size_t)b * 1024 + tt;
  float w0 = wgt[b * 2], w1 = wgt[b * 2 + 1];
  float4 xv = ((const float4*)(x + (size_t)row * Hh))[t];
  float4 a  = ((const float4*)(xk + r0 * Hh))[t];
  float4 c  = ((const float4*)(xk + (r0 + 512) * Hh))[t];
  float4 o;
  o.x = xv.x + w0 * a.x + w1 * c.x;
  o.y = xv.y + w0 * a.y + w1 * c.y;
  o.z = xv.z + w0 * a.z + w1 * c.z;
  o.w = xv.w + w0 * a.w + w1 * c.w;
  float ss = o.x * o.x + o.y * o.y + o.z * o.z + o.w * o.w;
  for (int off = 32; off; off >>= 1) ss += __shfl_xor(ss, off, 64);
  __shared__ float red[4];
  if ((t & 63) == 0) red[t >> 6] = ss;
  __syncthreads();
  float tot = red[0] + red[1] + red[2] + red[3];
  float scale = rsqrtf(tot * (1.f / (float)Hh) + 1.1920928955078125e-07f);
  float4 w4 = ((const float4*)nw)[t];
  ushort4 u;
  u.x = f2bf(o.x * scale * w4.x);
  u.y = f2bf(o.y * scale * w4.y);
  u.z = f2bf(o.z * scale * w4.z);
  u.w = f2bf(o.w * scale * w4.w);
  ((ushort4*)(xnb + (size_t)row * Hh))[t] = u;
}

extern "C" void kernel_launch(void* const* d_in, const int* in_sizes, int n_in,
                              void* d_out, int out_size, void* d_ws, size_t ws_size,
                              hipStream_t stream) {
  const int*   tokens = (const int*)d_in[0];
  const float* embed  = (const float*)d_in[1];
  const float* rw     = (const float*)d_in[2];
  const float* bw1    = (const float*)d_in[3];
  const float* bw2    = (const float*)d_in[4];
  const float* ew1    = (const float*)d_in[5];
  const float* ew2    = (const float*)d_in[6];
  const float* nw     = (const float*)d_in[7];
  const float* hw     = (const float*)d_in[8];
  float* out = (float*)d_out;

  char* p = (char*)d_ws;
  auto nxt = [&](size_t bytes) { char* r = p; p += (bytes + 255) & ~(size_t)255; return r; };
  float* x    = (float*)nxt((size_t)Mm * Hh * 4);
  u16*   xb   = (u16*)  nxt((size_t)Mm * Hh * 2);
  float* xk   = (float*)nxt((size_t)MKk * Hh * 4);
  u16*   xkb  = (u16*)  nxt((size_t)MKk * Hh * 2);
  u16*   hbuf = (u16*)  nxt((size_t)MKk * Ss * 2);
  u16*   w1t  = (u16*)  nxt((size_t)LMm * Ss * Hh * 2);
  u16*   w2t  = (u16*)  nxt((size_t)LMm * Hh * Ss * 2);
  u16*   e1t  = (u16*)  nxt((size_t)Ee * LEe * Ss * Hh * 2);
  u16*   e2t  = (u16*)  nxt((size_t)Ee * LEe * Hh * Ss * 2);
  u16*   hwb  = (u16*)  nxt((size_t)Vv * Hh * 2);
  float* part = (float*)nxt((size_t)64 * Hh * 4);
  int*   t2i  = (int*)  nxt(16 * 4);
  float* t2w  = (float*)nxt(16 * 4);

  // fused prep: weights + gather (1 dispatch)
  k_prep<<<16384, 256, 0, stream>>>(hw, hwb, bw1, w1t, bw2, w2t, ew1, e1t, ew2, e2t,
                                    tokens, embed, x, xb);

  // routing
  k_cmean1<<<64, 1024, 0, stream>>>(x, part);
  k_route<<<Bb, 1024, 0, stream>>>(part, rw, t2i, t2w);

  // backbone micro-layers (64x64 tiles)
  for (int l = 0; l < LMm; l++) {
    gemmS<0><<<(Mm/64)*(Ss/64), 256, 0, stream>>>(xb, w1t + (size_t)l * Ss * Hh,
        Mm/64, Ss, Hh, nullptr, nullptr, hbuf, nullptr, 0, 0, 0);
    gemmS<1><<<(Mm/64)*(Hh/64), 256, 0, stream>>>(hbuf, w2t + (size_t)l * Hh * Ss,
        Mm/64, Hh, Ss, x, x, xb, nullptr, 0, 0, 0);
  }

  // expert path (layer 0 reads x/xb through the broadcast row-map)
  gemmS<0><<<(MKk/64)*(Ss/64), 256, 0, stream>>>(xb, e1t,
      MKk/64, Ss, Hh, nullptr, nullptr, hbuf, t2i, (long long)LEe * Ss * Hh, 1, 0);
  gemmS<1><<<(MKk/64)*(Hh/64), 256, 0, stream>>>(hbuf, e2t,
      MKk/64, Hh, Ss, x, xk, xkb, t2i, (long long)LEe * Hh * Ss, 0, 1);
  gemmS<0><<<(MKk/64)*(Ss/64), 256, 0, stream>>>(xkb, e1t + (size_t)Ss * Hh,
      MKk/64, Ss, Hh, nullptr, nullptr, hbuf, t2i, (long long)LEe * Ss * Hh, 0, 0);
  gemmS<1><<<(MKk/64)*(Hh/64), 256, 0, stream>>>(hbuf, e2t + (size_t)Hh * Ss,
      MKk/64, Hh, Ss, xk, xk, xkb, t2i, (long long)LEe * Hh * Ss, 0, 0);

  // fused combine + RMSNorm -> bf16, then head GEMM (read-ahead 8-phase)
  k_combnorm<<<Mm, 256, 0, stream>>>(x, xk, t2w, nw, xb);
  gemm256<<<(Mm/256)*(Vv/256), 1024, 0, stream>>>(xb, hwb, Vv/256, Vv, Hh, out);
}

// Round 15
// 555.084 us; speedup vs baseline: 1.0666x; 1.0666x over previous
//
#include <hip/hip_runtime.h>
#include <stdint.h>

#define Bb 8
#define Tt 512
#define Vv 32000
#define Hh 1024
#define Ss 256
#define Ee 8
#define LEe 2
#define LMm 4
#define Mm (Bb*Tt)        // 4096
#define MKk (Bb*2*Tt)     // 8192

typedef unsigned short u16;
typedef __bf16 bf16x8 __attribute__((ext_vector_type(8)));
typedef float f32x4 __attribute__((ext_vector_type(4)));

__device__ __forceinline__ u16 f2bf(float f) {
  union { float f; uint32_t u; } c; c.f = f;
  uint32_t u = c.u;
  uint32_t r = (u + 0x7FFFu + ((u >> 16) & 1u)) >> 16;
  return (u16)r;
}

// strongest available cache-bypass store: system-scope + non-temporal.
// Goal: stop the 512MB f32 output stream from write-allocating in L2/L3 and
// evicting the B panels (FETCH 533MB vs 73MB ideal = the head's real wall).
__device__ __forceinline__ void st_bypass(float* p, float v) {
  asm volatile("global_store_dword %0, %1, off sc0 sc1 nt"
               :: "v"(p), "v"(v) : "memory");
}

// ---------------------------------------------------------------------------
// 256x256 bf16 MFMA GEMM (head), 8-phase, 16 waves, read-ahead (r14 config),
// output stores via sc0+sc1+nt bypass.
// ---------------------------------------------------------------------------
#define PH(MH_C, AS_C, BS_C, AN_CUR, AN_KH, AN_MH, AS_N, RDB, BN_CUR, BN_KH, BS_N, STAGECALL, WAITV) \
  {                                                                            \
    STAGECALL;                                                                 \
    __builtin_amdgcn_sched_barrier(0);                                         \
    __builtin_amdgcn_s_barrier();                                              \
    asm volatile("s_waitcnt lgkmcnt(0)" ::: "memory");                         \
    __builtin_amdgcn_sched_barrier(0);                                         \
    if (!(WAITV)) {                                                            \
      af[AS_N][0] = *(const bf16x8*)&As[AN_CUR][AN_KH][aoffs[(AN_MH)*2]];      \
      af[AS_N][1] = *(const bf16x8*)&As[AN_CUR][AN_KH][aoffs[(AN_MH)*2+1]];    \
      if (RDB) {                                                               \
        _Pragma("unroll")                                                      \
        for (int ni = 0; ni < 4; ni++)                                         \
          bf2[BS_N][ni] = *(const bf16x8*)&Bs[BN_CUR][BN_KH][boffs[ni]];       \
      }                                                                        \
    }                                                                          \
    __builtin_amdgcn_s_setprio(1);                                             \
    _Pragma("unroll")                                                          \
    for (int ni = 0; ni < 4; ni++) {                                           \
      acc[(MH_C)*2][ni]   = __builtin_amdgcn_mfma_f32_16x16x32_bf16(af[AS_C][0], bf2[BS_C][ni], acc[(MH_C)*2][ni], 0, 0, 0);   \
      acc[(MH_C)*2+1][ni] = __builtin_amdgcn_mfma_f32_16x16x32_bf16(af[AS_C][1], bf2[BS_C][ni], acc[(MH_C)*2+1][ni], 0, 0, 0); \
    }                                                                          \
    __builtin_amdgcn_s_setprio(0);                                             \
    __builtin_amdgcn_sched_barrier(0);                                         \
    if (WAITV) {                                                               \
      asm volatile("s_waitcnt vmcnt(2)" ::: "memory");                         \
      af[AS_N][0] = *(const bf16x8*)&As[AN_CUR][AN_KH][aoffs[(AN_MH)*2]];      \
      af[AS_N][1] = *(const bf16x8*)&As[AN_CUR][AN_KH][aoffs[(AN_MH)*2+1]];    \
      if (RDB) {                                                               \
        _Pragma("unroll")                                                      \
        for (int ni = 0; ni < 4; ni++)                                         \
          bf2[BS_N][ni] = *(const bf16x8*)&Bs[BN_CUR][BN_KH][boffs[ni]];       \
      }                                                                        \
    }                                                                          \
    __builtin_amdgcn_s_barrier();                                              \
    __builtin_amdgcn_sched_barrier(0);                                         \
  }

__global__ __launch_bounds__(1024, 2)
void gemm256(const u16* __restrict__ A, const u16* __restrict__ Bw,
             int nbn, int N, int K, float* __restrict__ outF)
{
  __shared__ u16 As[2][2][256*32];
  __shared__ u16 Bs[2][2][256*32];

  const int id  = blockIdx.x;
  const int per = gridDim.x >> 3;
  const int vid = (id & 7) * per + (id >> 3);
  const int bn  = vid % nbn;
  const int bm  = vid / nbn;

  const int t = threadIdx.x;
  const int lane = t & 63;
  const int w = t >> 6;
  const int wr = w >> 2, wc = w & 3;
  const int l16 = lane & 15, lhi = lane >> 4;

  const long long arow0 = (long long)bm * 256;
  const long long brow0 = (long long)bn * 256;

  int aoffs[4], boffs[4];
#pragma unroll
  for (int mi = 0; mi < 4; mi++) {
    const int r = wr * 64 + mi * 16 + l16;
    aoffs[mi] = r * 32 + (lhi ^ ((r >> 1) & 3)) * 8;
  }
#pragma unroll
  for (int ni = 0; ni < 4; ni++) {
    const int r = wc * 64 + ni * 16 + l16;
    boffs[ni] = r * 32 + (lhi ^ ((r >> 1) & 3)) * 8;
  }

  const int sr = t >> 2;
  const int sc = (t & 3) ^ ((sr >> 1) & 3);
  const long long sAo = (arow0 + sr) * (long long)K + sc * 8;
  const long long sBo = (brow0 + sr) * (long long)K + sc * 8;
  const int ldsd = t * 8;

  f32x4 acc[4][4];
#pragma unroll
  for (int i = 0; i < 4; i++)
#pragma unroll
    for (int j = 0; j < 4; j++) acc[i][j] = (f32x4){0.f, 0.f, 0.f, 0.f};

  auto SA = [&](int b, int kh, int k0) {
    __builtin_amdgcn_global_load_lds(
        (const __attribute__((address_space(1))) void*)(A + sAo + k0 + kh * 32),
        (__attribute__((address_space(3))) void*)(&As[b][kh][ldsd]), 16, 0, 0);
  };
  auto SB = [&](int b, int kh, int k0) {
    __builtin_amdgcn_global_load_lds(
        (const __attribute__((address_space(1))) void*)(Bw + sBo + k0 + kh * 32),
        (__attribute__((address_space(3))) void*)(&Bs[b][kh][ldsd]), 16, 0, 0);
  };

  bf16x8 af[2][2];
  bf16x8 bf2[2][4];

  const int NT = K >> 6;

  SA(0, 0, 0); SB(0, 0, 0);
  SA(0, 1, 0); SB(0, 1, 0);
  SA(1, 0, 64); SB(1, 0, 64);
  asm volatile("s_waitcnt vmcnt(2)" ::: "memory");
  __builtin_amdgcn_s_barrier();
  af[0][0] = *(const bf16x8*)&As[0][0][aoffs[0]];
  af[0][1] = *(const bf16x8*)&As[0][0][aoffs[1]];
#pragma unroll
  for (int ni = 0; ni < 4; ni++)
    bf2[0][ni] = *(const bf16x8*)&Bs[0][0][boffs[ni]];
  __builtin_amdgcn_sched_barrier(0);

  for (int it = 0; it < (NT >> 1); ++it) {
    const int k1 = (2 * it + 1) << 6;
    const int t2 = 2 * it + 2, t3 = 2 * it + 3;
    const int k2 = (t2 < NT ? t2 : NT - 1) << 6;
    const int k3 = (t3 < NT ? t3 : NT - 1) << 6;
    PH(0, 0, 0,  0, 0, 1, 1,  0, 0, 0, 0, SA(1, 1, k1), 0)   // P1
    PH(1, 1, 0,  0, 1, 0, 0,  1, 0, 1, 1, SB(1, 1, k1), 0)   // P2
    PH(0, 0, 1,  0, 1, 1, 1,  0, 0, 0, 0, SA(0, 0, k2), 0)   // P3
    PH(1, 1, 1,  1, 0, 0, 0,  1, 1, 0, 0, SB(0, 0, k2), 1)   // P4
    PH(0, 0, 0,  1, 0, 1, 1,  0, 0, 0, 0, SA(0, 1, k2), 0)   // P5
    PH(1, 1, 0,  1, 1, 0, 0,  1, 1, 1, 1, SB(0, 1, k2), 0)   // P6
    PH(0, 0, 1,  1, 1, 1, 1,  0, 0, 0, 0, SA(1, 0, k3), 0)   // P7
    PH(1, 1, 1,  0, 0, 0, 0,  1, 0, 0, 0, SB(1, 0, k3), 1)   // P8
  }

#pragma unroll
  for (int mi = 0; mi < 4; mi++) {
#pragma unroll
    for (int rr = 0; rr < 4; rr++) {
      const long long grow = arow0 + wr * 64 + mi * 16 + lhi * 4 + rr;
#pragma unroll
      for (int ni = 0; ni < 4; ni++) {
        const long long gcol = brow0 + wc * 64 + ni * 16 + l16;
        st_bypass(&outF[grow * N + gcol], acc[mi][ni][rr]);
      }
    }
  }
}

// ---------------------------------------------------------------------------
// Small GEMM, 64x64 tile, 4 waves, 4 blocks/CU. All small/mid GEMMs.
// ---------------------------------------------------------------------------
template<int MODE>
__global__ __launch_bounds__(256, 4)
void gemmS(const u16* __restrict__ A, const u16* __restrict__ Bw,
           int nbm, int N, int K,
           const float* __restrict__ res, float* __restrict__ outF,
           u16* __restrict__ outB,
           const int* __restrict__ esel, long long estride,
           int mapA, int mapRes)
{
  __shared__ u16 As[2][64*64];
  __shared__ u16 Bs[2][64*64];

  const int id  = blockIdx.x;
  const int per = gridDim.x >> 3;
  const int vid = (id & 7) * per + (id >> 3);
  const int bm  = vid % nbm;
  const int bn  = vid / nbm;

  const int t = threadIdx.x;
  const int w = t >> 6, lane = t & 63;
  const int wr = w >> 1, wc = w & 1;
  const int l16 = lane & 15, lhi = lane >> 4;

  const u16* Bp = Bw;
  if (esel) Bp += (long long)esel[bm >> 3] * estride;

  const long long mrow0 = (long long)(bm >> 4) * 512 + (long long)(bm & 7) * 64;
  const long long arow0 = (long long)bm * 64;
  const long long asrc0 = mapA ? mrow0 : arow0;
  const long long rrow0 = mapRes ? mrow0 : arow0;
  const long long brow0 = (long long)bn * 64;

  long long aoff[2], boff[2];
  int ldso[2];
#pragma unroll
  for (int i = 0; i < 2; ++i) {
    const int g  = i * 256 + t;
    const int r  = g >> 3;
    const int pc = g & 7;
    const int c  = pc ^ (r & 7);
    aoff[i] = (asrc0 + r) * (long long)K + c * 8;
    boff[i] = (brow0 + r) * (long long)K + c * 8;
    ldso[i] = g * 8;
  }

  f32x4 acc[2][2];
#pragma unroll
  for (int i = 0; i < 2; i++)
#pragma unroll
    for (int j = 0; j < 2; j++) acc[i][j] = (f32x4){0.f, 0.f, 0.f, 0.f};

  auto STAGE = [&](int bsel, int k0) {
#pragma unroll
    for (int i = 0; i < 2; ++i)
      __builtin_amdgcn_global_load_lds(
          (const __attribute__((address_space(1))) void*)(A + aoff[i] + k0),
          (__attribute__((address_space(3))) void*)(&As[bsel][ldso[i]]), 16, 0, 0);
#pragma unroll
    for (int i = 0; i < 2; ++i)
      __builtin_amdgcn_global_load_lds(
          (const __attribute__((address_space(1))) void*)(Bp + boff[i] + k0),
          (__attribute__((address_space(3))) void*)(&Bs[bsel][ldso[i]]), 16, 0, 0);
  };

  const int rowA = (wr * 32 + l16) * 64;
  const int rowB = (wc * 32 + l16) * 64;
  const int x7   = l16 & 7;

  const int NT = K >> 6;

  STAGE(0, 0);
  asm volatile("s_waitcnt vmcnt(0)" ::: "memory");
  __builtin_amdgcn_s_barrier();

  for (int tile = 0; tile < NT; ++tile) {
    const int cur = tile & 1;
    if (tile + 1 < NT) STAGE(cur ^ 1, (tile + 1) << 6);

#pragma unroll
    for (int s = 0; s < 2; ++s) {
      bf16x8 af[2], bfv[2];
      const int swz = ((s * 4 + lhi) ^ x7) * 8;
#pragma unroll
      for (int mi = 0; mi < 2; mi++)
        af[mi] = *(const bf16x8*)&As[cur][rowA + mi * 1024 + swz];
#pragma unroll
      for (int ni = 0; ni < 2; ni++)
        bfv[ni] = *(const bf16x8*)&Bs[cur][rowB + ni * 1024 + swz];
      __builtin_amdgcn_s_setprio(1);
#pragma unroll
      for (int mi = 0; mi < 2; mi++)
#pragma unroll
        for (int ni = 0; ni < 2; ni++)
          acc[mi][ni] = __builtin_amdgcn_mfma_f32_16x16x32_bf16(af[mi], bfv[ni], acc[mi][ni], 0, 0, 0);
      __builtin_amdgcn_s_setprio(0);
    }

    if (tile + 1 < NT) {
      asm volatile("s_waitcnt vmcnt(0)" ::: "memory");
      __builtin_amdgcn_s_barrier();
    }
  }

#pragma unroll
  for (int mi = 0; mi < 2; mi++) {
#pragma unroll
    for (int rr = 0; rr < 4; rr++) {
      const long long lrow = wr * 32 + mi * 16 + lhi * 4 + rr;
      const long long grow = arow0 + lrow;
#pragma unroll
      for (int ni = 0; ni < 2; ni++) {
        const long long gcol = brow0 + wc * 32 + ni * 16 + l16;
        const long long idx  = grow * N + gcol;
        float v = acc[mi][ni][rr];
        if (MODE == 0) {
          float s = v / (1.f + expf(-v));
          outB[idx] = f2bf(s);
        } else {
          float o = res[(rrow0 + lrow) * N + gcol] + 0.1f * v;
          outF[idx] = o;
          outB[idx] = f2bf(o);
        }
      }
    }
  }
}

// ---------------------------------------------------------------------------
// Fused prep: ONE dispatch for head cvt + 4 weight transposes + embed gather.
// ---------------------------------------------------------------------------
__device__ __forceinline__ void tr_tile(const float* __restrict__ in,
                                        u16* __restrict__ out,
                                        int R, int C, int j, int t) {
  __shared__ float tile[32][33];
  const int ntx = C >> 5, nty = R >> 5;
  const int b = j / (ntx * nty);
  const int rem = j % (ntx * nty);
  const int c0 = (rem % ntx) * 32, r0 = (rem / ntx) * 32;
  const float* src = in  + (size_t)b * R * C;
  u16*         dst = out + (size_t)b * R * C;
  const int tx = t & 31, ty = t >> 5;
#pragma unroll
  for (int i = 0; i < 4; ++i)
    tile[ty * 4 + i][tx] = src[(size_t)(r0 + ty * 4 + i) * C + c0 + tx];
  __syncthreads();
#pragma unroll
  for (int i = 0; i < 4; ++i)
    dst[(size_t)(c0 + ty * 4 + i) * R + r0 + tx] = f2bf(tile[tx][ty * 4 + i]);
}

__global__ __launch_bounds__(256)
void k_prep(const float* __restrict__ hw, u16* __restrict__ hwb,
            const float* __restrict__ bw1, u16* __restrict__ w1t,
            const float* __restrict__ bw2, u16* __restrict__ w2t,
            const float* __restrict__ ew1, u16* __restrict__ e1t,
            const float* __restrict__ ew2, u16* __restrict__ e2t,
            const int* __restrict__ tokens, const float* __restrict__ embed,
            float* __restrict__ x, u16* __restrict__ xb)
{
  const int bid = blockIdx.x;
  const int t = threadIdx.x;
  if (bid < 2048) {
    const size_t n4 = (size_t)Vv * Hh / 4;
    for (size_t i = (size_t)bid * 256 + t; i < n4; i += 2048 * 256) {
      float4 v = ((const float4*)hw)[i];
      ushort4 u;
      u.x = f2bf(v.x); u.y = f2bf(v.y); u.z = f2bf(v.z); u.w = f2bf(v.w);
      ((ushort4*)hwb)[i] = u;
    }
  } else if (bid < 3072) {
    tr_tile(bw1, w1t, Hh, Ss, bid - 2048, t);
  } else if (bid < 4096) {
    tr_tile(bw2, w2t, Ss, Hh, bid - 3072, t);
  } else if (bid < 8192) {
    tr_tile(ew1, e1t, Hh, Ss, bid - 4096, t);
  } else if (bid < 12288) {
    tr_tile(ew2, e2t, Ss, Hh, bid - 8192, t);
  } else {
    const int row = bid - 12288;
    const int tok = tokens[row];
    float4 v = ((const float4*)(embed + (size_t)tok * Hh))[t];
    ((float4*)(x + (size_t)row * Hh))[t] = v;
    ushort4 u;
    u.x = f2bf(v.x); u.y = f2bf(v.y); u.z = f2bf(v.z); u.w = f2bf(v.w);
    ((ushort4*)(xb + (size_t)row * Hh))[t] = u;
  }
}

// column-mean stage 1
__global__ __launch_bounds__(1024) void k_cmean1(const float* __restrict__ x, float* __restrict__ part) {
  int b = blockIdx.x >> 3, ch = blockIdx.x & 7;
  int col = threadIdx.x;
  float s = 0.f;
  for (int t = ch * 64; t < ch * 64 + 64; ++t)
    s += x[((size_t)b * Tt + t) * Hh + col];
  part[(size_t)blockIdx.x * Hh + col] = s;
}

// routing: 8 blocks (one per sequence), 1024 threads
__global__ __launch_bounds__(1024) void k_route(const float* __restrict__ part,
                                                const float* __restrict__ rw,
                                                int* __restrict__ t2i, float* __restrict__ t2w) {
  __shared__ float xm[Hh];
  __shared__ float lg[16];
  const int b = blockIdx.x;
  const int t = threadIdx.x;
  float s = 0.f;
#pragma unroll
  for (int ch = 0; ch < 8; ch++) s += part[(size_t)(b * 8 + ch) * Hh + t];
  xm[t] = s;
  __syncthreads();
  const int w = t >> 6, lane = t & 63;
  if (w < Ee) {
    float d = 0.f;
    for (int j = lane; j < Hh; j += 64)
      d += xm[j] * rw[(size_t)w * Hh + j];
    for (int off = 32; off; off >>= 1) d += __shfl_xor(d, off, 64);
    if (lane == 0) lg[w] = d * (2.f / (float)Tt);
  }
  __syncthreads();
  if (t == 0) {
    float logits[Ee];
#pragma unroll
    for (int e = 0; e < Ee; e++) logits[e] = lg[e];
    float mx = logits[0];
    for (int e = 1; e < Ee; e++) mx = fmaxf(mx, logits[e]);
    float pr[Ee], den = 0.f;
    for (int e = 0; e < Ee; e++) { pr[e] = expf(logits[e] - mx); den += pr[e]; }
    for (int e = 0; e < Ee; e++) pr[e] /= den;
    int i1 = 0;
    for (int e = 1; e < Ee; e++) if (pr[e] > pr[i1]) i1 = e;
    int i2 = -1;
    for (int e = 0; e < Ee; e++) { if (e == i1) continue; if (i2 < 0 || pr[e] > pr[i2]) i2 = e; }
    float eb = expf(pr[i2] - pr[i1]);
    float w0 = 1.f / (1.f + eb);
    float w1 = eb / (1.f + eb);
    t2i[b * 2]     = i1;  t2i[b * 2 + 1] = i2;
    t2w[b * 2]     = w0;  t2w[b * 2 + 1] = w1;
  }
}

// fused combine + RMSNorm: o = x + w0*xk[b,0] + w1*xk[b,1]; xb = bf16(rms(o))
__global__ __launch_bounds__(256) void k_combnorm(const float* __restrict__ x,
                                                  const float* __restrict__ xk,
                                                  const float* __restrict__ wgt,
                                                  const float* __restrict__ nw,
                                                  u16* __restrict__ xnb) {
  int row = blockIdx.x, t = threadIdx.x;
  int b = row >> 9, tt = row & 511;
  size_t r0 = (size_t)b * 1024 + tt;
  float w0 = wgt[b * 2], w1 = wgt[b * 2 + 1];
  float4 xv = ((const float4*)(x + (size_t)row * Hh))[t];
  float4 a  = ((const float4*)(xk + r0 * Hh))[t];
  float4 c  = ((const float4*)(xk + (r0 + 512) * Hh))[t];
  float4 o;
  o.x = xv.x + w0 * a.x + w1 * c.x;
  o.y = xv.y + w0 * a.y + w1 * c.y;
  o.z = xv.z + w0 * a.z + w1 * c.z;
  o.w = xv.w + w0 * a.w + w1 * c.w;
  float ss = o.x * o.x + o.y * o.y + o.z * o.z + o.w * o.w;
  for (int off = 32; off; off >>= 1) ss += __shfl_xor(ss, off, 64);
  __shared__ float red[4];
  if ((t & 63) == 0) red[t >> 6] = ss;
  __syncthreads();
  float tot = red[0] + red[1] + red[2] + red[3];
  float scale = rsqrtf(tot * (1.f / (float)Hh) + 1.1920928955078125e-07f);
  float4 w4 = ((const float4*)nw)[t];
  ushort4 u;
  u.x = f2bf(o.x * scale * w4.x);
  u.y = f2bf(o.y * scale * w4.y);
  u.z = f2bf(o.z * scale * w4.z);
  u.w = f2bf(o.w * scale * w4.w);
  ((ushort4*)(xnb + (size_t)row * Hh))[t] = u;
}

extern "C" void kernel_launch(void* const* d_in, const int* in_sizes, int n_in,
                              void* d_out, int out_size, void* d_ws, size_t ws_size,
                              hipStream_t stream) {
  const int*   tokens = (const int*)d_in[0];
  const float* embed  = (const float*)d_in[1];
  const float* rw     = (const float*)d_in[2];
  const float* bw1    = (const float*)d_in[3];
  const float* bw2    = (const float*)d_in[4];
  const float* ew1    = (const float*)d_in[5];
  const float* ew2    = (const float*)d_in[6];
  const float* nw     = (const float*)d_in[7];
  const float* hw     = (const float*)d_in[8];
  float* out = (float*)d_out;

  char* p = (char*)d_ws;
  auto nxt = [&](size_t bytes) { char* r = p; p += (bytes + 255) & ~(size_t)255; return r; };
  float* x    = (float*)nxt((size_t)Mm * Hh * 4);
  u16*   xb   = (u16*)  nxt((size_t)Mm * Hh * 2);
  float* xk   = (float*)nxt((size_t)MKk * Hh * 4);
  u16*   xkb  = (u16*)  nxt((size_t)MKk * Hh * 2);
  u16*   hbuf = (u16*)  nxt((size_t)MKk * Ss * 2);
  u16*   w1t  = (u16*)  nxt((size_t)LMm * Ss * Hh * 2);
  u16*   w2t  = (u16*)  nxt((size_t)LMm * Hh * Ss * 2);
  u16*   e1t  = (u16*)  nxt((size_t)Ee * LEe * Ss * Hh * 2);
  u16*   e2t  = (u16*)  nxt((size_t)Ee * LEe * Hh * Ss * 2);
  u16*   hwb  = (u16*)  nxt((size_t)Vv * Hh * 2);
  float* part = (float*)nxt((size_t)64 * Hh * 4);
  int*   t2i  = (int*)  nxt(16 * 4);
  float* t2w  = (float*)nxt(16 * 4);

  // fused prep: weights + gather (1 dispatch)
  k_prep<<<16384, 256, 0, stream>>>(hw, hwb, bw1, w1t, bw2, w2t, ew1, e1t, ew2, e2t,
                                    tokens, embed, x, xb);

  // routing
  k_cmean1<<<64, 1024, 0, stream>>>(x, part);
  k_route<<<Bb, 1024, 0, stream>>>(part, rw, t2i, t2w);

  // backbone micro-layers (64x64 tiles)
  for (int l = 0; l < LMm; l++) {
    gemmS<0><<<(Mm/64)*(Ss/64), 256, 0, stream>>>(xb, w1t + (size_t)l * Ss * Hh,
        Mm/64, Ss, Hh, nullptr, nullptr, hbuf, nullptr, 0, 0, 0);
    gemmS<1><<<(Mm/64)*(Hh/64), 256, 0, stream>>>(hbuf, w2t + (size_t)l * Hh * Ss,
        Mm/64, Hh, Ss, x, x, xb, nullptr, 0, 0, 0);
  }

  // expert path (layer 0 reads x/xb through the broadcast row-map)
  gemmS<0><<<(MKk/64)*(Ss/64), 256, 0, stream>>>(xb, e1t,
      MKk/64, Ss, Hh, nullptr, nullptr, hbuf, t2i, (long long)LEe * Ss * Hh, 1, 0);
  gemmS<1><<<(MKk/64)*(Hh/64), 256, 0, stream>>>(hbuf, e2t,
      MKk/64, Hh, Ss, x, xk, xkb, t2i, (long long)LEe * Hh * Ss, 0, 1);
  gemmS<0><<<(MKk/64)*(Ss/64), 256, 0, stream>>>(xkb, e1t + (size_t)Ss * Hh,
      MKk/64, Ss, Hh, nullptr, nullptr, hbuf, t2i, (long long)LEe * Ss * Hh, 0, 0);
  gemmS<1><<<(MKk/64)*(Hh/64), 256, 0, stream>>>(hbuf, e2t + (size_t)Hh * Ss,
      MKk/64, Hh, Ss, xk, xk, xkb, t2i, (long long)LEe * Hh * Ss, 0, 0);

  // fused combine + RMSNorm -> bf16, then head GEMM (bypass-store epilogue)
  k_combnorm<<<Mm, 256, 0, stream>>>(x, xk, t2w, nw, xb);
  gemm256<<<(Mm/256)*(Vv/256), 1024, 0, stream>>>(xb, hwb, Vv/256, Vv, Hh, out);
}